// Round 9
// baseline (133.207 us; speedup 1.0000x reference)
//
#include <hip/hip_runtime.h>

// DeformConv3D_alternative: B=1, C=16->16, S=32, ks=3, N=27, fp32.
// R9: R8 unchanged except cache policy: offset staging loads + output stores
// are NONTEMPORAL (nt flag, evict-first). Theory: the 10.6 MB offset stream
// evicts the 2.5 MB xp from each XCD's 4 MB L2 (FETCH 26.4 MB vs ~17.6 MB
// compulsory => ~9 MB re-fetch), pushing gather fills to L3/HBM (~400+ cyc).
// Plateau fits 64-outstanding-fills x 400cyc: 27.6K lines/CU x 400/64 = 168K
// cyc = 70 us. Keeping xp L2-resident should ~halve fill latency.
// Fixed ~58 us harness overhead (restore+poison) measured across R0-R8.

#define NCH 16
#define PADDIM 34
#define PLANE 32768            // 32*32*32

__device__ __forceinline__ float4 f4fma(float s, const float4 a, const float4 b) {
  return make_float4(fmaf(s, a.x, b.x), fmaf(s, a.y, b.y),
                     fmaf(s, a.z, b.z), fmaf(s, a.w, b.w));
}
__device__ __forceinline__ float4 f4scale(float s, const float4 a) {
  return make_float4(s * a.x, s * a.y, s * a.z, s * a.w);
}

// Reference semantics: q0=clip(floor(p),0,33), q1=clip(floor(p)+1,0,33);
// mask=(p<1)|(p>32) -> p=floor(p); p=clip(p,0,33); l=1+q0-p; h=1-q1+p.
__device__ __forceinline__ void axis_interp(float p, int& q0, int& q1,
                                            float& lo, float& hi) {
  float fl = floorf(p);
  int fi = (int)fl;
  q0 = min(max(fi, 0), 33);
  q1 = min(max(fi + 1, 0), 33);
  float pm = (p < 1.f || p > 32.f) ? fl : p;
  pm = fminf(fmaxf(pm, 0.f), 33.f);
  lo = 1.f + (float)q0 - pm;
  hi = 1.f - (float)q1 + pm;
}

// ---- single prep kernel: xp (padded channel-last x) + Wt transpose
__global__ void prep_small(const float* __restrict__ x,
                           const float* __restrict__ W,
                           float* __restrict__ xp, float* __restrict__ wt) {
  int b = blockIdx.x;
  if (b < 2457) {
    int idx = b * 256 + threadIdx.x;
    if (idx >= PADDIM * PADDIM * PADDIM * NCH) return;
    int c = idx & 15;
    int site = idx >> 4;
    int qz = site % PADDIM;
    int t = site / PADDIM;
    int qy = t % PADDIM;
    int qx = t / PADDIM;
    float v = 0.f;
    if (qx >= 1 && qx <= 32 && qy >= 1 && qy <= 32 && qz >= 1 && qz <= 32)
      v = x[c * PLANE + ((qx - 1) * 32 + (qy - 1)) * 32 + (qz - 1)];
    xp[idx] = v;
  } else {
    int idx = (b - 2457) * 256 + threadIdx.x;   // [0, 6912)
    if (idx >= 6912) return;
    int o = idx & 15;
    int r = idx >> 4;
    int cw = r & 15;
    int t = r >> 4;
    wt[idx] = W[(o * 16 + cw) * 27 + t];        // Wt[t][cin][o]
  }
}

// ---- main: tid = kk(4b) | c4(2b) | kh(1b) | th(2b); grid = 1024 (i,j).
// wave (64 lanes) = 16 kk x 4 c4 -> each site's 64B line coalesces fully.
__global__ __launch_bounds__(512, 8) void deform_main9(
    const float* __restrict__ off, const float* __restrict__ Wt,
    const float* __restrict__ xp, float* __restrict__ out) {
  __shared__ float sOff[2916];       // 3 comp * 3 alpha * 27 n * 12 pos
  __shared__ float red[4][32][20];   // [th][k][o(+pad)]

  int tid = threadIdx.x;
  int b = blockIdx.x;
  int i = b >> 5;
  int j = b & 31;

  // --- stage offset working set into LDS; NONTEMPORAL (don't pollute L2) ---
#pragma unroll
  for (int it = 0; it < 6; it++) {
    int s = tid + it * 512;
    if (s < 2916) {
      int comp = s / 972;
      int rem = s - comp * 972;
      int alpha = rem / 324;
      int rem2 = rem - alpha * 324;
      int n = rem2 / 12;
      int pos = rem2 - n * 12;
      int aj = 2 * alpha + j;
      int r3 = aj % 3;
      int wp = 10 * alpha + aj / 3;
      int dp = min((r3 * 96) / 9 + pos, 31);
      sOff[s] = __builtin_nontemporal_load(
          &off[(comp * 27 + n) * PLANE + i * 1024 + wp * 32 + dp]);
    }
  }
  __syncthreads();

  int kk = tid & 15;                 // k within half
  int c4 = (tid >> 4) & 3;           // channel quad (4 per wave -> full line)
  int kh = (tid >> 6) & 1;           // k half
  int th = tid >> 7;                 // tap phase: t = th, th+4, ...
  int k = kh * 16 + kk;

  float4 acc0 = make_float4(0.f, 0.f, 0.f, 0.f);
  float4 acc1 = acc0, acc2 = acc0, acc3 = acc0;

  const float4* xp4 = (const float4*)xp;
  const float4* Wt4 = (const float4*)Wt;

  for (int t = th; t < 27; t += 4) {
    int alpha = t / 9;
    int t3 = t / 3;
    int beta = t3 % 3;
    int gamma = t - t3 * 3;
    int G = 3072 * alpha + 96 * j + 3 * k + gamma;
    int wp = G / 288;
    int u = G - wp * 288;
    int dp = u / 9;
    int m = u - dp * 9;
    int n = 9 * beta + m;
    int aj = 2 * alpha + j;
    int dp_lo = ((aj % 3) * 96) / 9;
    int lidx = (alpha * 27 + n) * 12 + (dp - dp_lo);

    float ox = sOff[lidx];
    float oy = sOff[lidx + 972];
    float oz = sOff[lidx + 1944];

    int md3 = m / 3;
    float px = (float)(i + beta) + ox;
    float py = (float)(wp + md3) + oy;
    float pz = (float)(dp + m - md3 * 3) + oz;

    int q0x, q1x, q0y, q1y, q0z, q1z;
    float lx, hx, ly, hy, lz, hz;
    axis_interp(px, q0x, q1x, lx, hx);
    axis_interp(py, q0y, q1y, ly, hy);
    axis_interp(pz, q0z, q1z, lz, hz);

    float a00 = ly * lz, a01 = ly * hz, a10 = hy * lz, a11 = hy * hz;
    float w000 = lx * a00, w001 = lx * a01, w010 = lx * a10, w011 = lx * a11;
    float w100 = hx * a00, w101 = hx * a01, w110 = hx * a10, w111 = hx * a11;

    int b00 = (q0x * PADDIM + q0y) * PADDIM;
    int b01 = (q0x * PADDIM + q1y) * PADDIM;
    int b10 = (q1x * PADDIM + q0y) * PADDIM;
    int b11 = (q1x * PADDIM + q1y) * PADDIM;
    float4 s4;
    s4 = f4scale(w000, xp4[(b00 + q0z) * 4 + c4]);
    s4 = f4fma(w001, xp4[(b00 + q1z) * 4 + c4], s4);
    s4 = f4fma(w010, xp4[(b01 + q0z) * 4 + c4], s4);
    s4 = f4fma(w011, xp4[(b01 + q1z) * 4 + c4], s4);
    s4 = f4fma(w100, xp4[(b10 + q0z) * 4 + c4], s4);
    s4 = f4fma(w101, xp4[(b10 + q1z) * 4 + c4], s4);
    s4 = f4fma(w110, xp4[(b11 + q0z) * 4 + c4], s4);
    s4 = f4fma(w111, xp4[(b11 + q1z) * 4 + c4], s4);

    float sarr[4] = {s4.x, s4.y, s4.z, s4.w};
    int wb = t * 64 + c4 * 16;
#pragma unroll
    for (int cc = 0; cc < 4; cc++) {
      float s = sarr[cc];
      acc0 = f4fma(s, Wt4[wb + cc * 4 + 0], acc0);
      acc1 = f4fma(s, Wt4[wb + cc * 4 + 1], acc1);
      acc2 = f4fma(s, Wt4[wb + cc * 4 + 2], acc2);
      acc3 = f4fma(s, Wt4[wb + cc * 4 + 3], acc3);
    }
  }

  // --- reduce across c4 (lane bits 4,5) in-wave ---
#pragma unroll
  for (int mask = 16; mask <= 32; mask <<= 1) {
    acc0.x += __shfl_xor(acc0.x, mask); acc0.y += __shfl_xor(acc0.y, mask);
    acc0.z += __shfl_xor(acc0.z, mask); acc0.w += __shfl_xor(acc0.w, mask);
    acc1.x += __shfl_xor(acc1.x, mask); acc1.y += __shfl_xor(acc1.y, mask);
    acc1.z += __shfl_xor(acc1.z, mask); acc1.w += __shfl_xor(acc1.w, mask);
    acc2.x += __shfl_xor(acc2.x, mask); acc2.y += __shfl_xor(acc2.y, mask);
    acc2.z += __shfl_xor(acc2.z, mask); acc2.w += __shfl_xor(acc2.w, mask);
    acc3.x += __shfl_xor(acc3.x, mask); acc3.y += __shfl_xor(acc3.y, mask);
    acc3.z += __shfl_xor(acc3.z, mask); acc3.w += __shfl_xor(acc3.w, mask);
  }

  if (c4 == 0) {
    float* r = &red[th][k][0];
    ((float4*)r)[0] = acc0;
    ((float4*)r)[1] = acc1;
    ((float4*)r)[2] = acc2;
    ((float4*)r)[3] = acc3;
  }
  __syncthreads();

  // --- 4-way tap-phase reduction + nontemporal store ---
  int o = tid >> 5;                  // 0..15
  int kr = tid & 31;
  float v = red[0][kr][o] + red[1][kr][o] + red[2][kr][o] + red[3][kr][o];
  __builtin_nontemporal_store(v, &out[((o * 32 + i) * 32 + j) * 32 + kr]);
}

// ---- fallback (no workspace): direct bounds-checked reads, 1 kernel
__device__ __forceinline__ void tap_meta(int t, int i, int j, int k,
                                         int& src, float& bx, float& by,
                                         float& bz) {
  int alpha = t / 9;
  int beta = (t / 3) % 3;
  int gamma = t - (t / 3) * 3;
  int G = 3072 * alpha + 96 * j + 3 * k + gamma;
  int wp = G / 288;
  int u = G - wp * 288;
  int dp = u / 9;
  int m = u - dp * 9;
  int n = 9 * beta + m;
  src = n * PLANE + i * 1024 + wp * 32 + dp;
  int md3 = m / 3;
  bx = (float)(i + beta);
  by = (float)(wp + md3);
  bz = (float)(dp + m - md3 * 3);
}

__device__ __forceinline__ float4 corner_direct(const float* __restrict__ x,
                                                int qx, int qy, int qz, int c0) {
  if (qx < 1 || qx > 32 || qy < 1 || qy > 32 || qz < 1 || qz > 32)
    return make_float4(0.f, 0.f, 0.f, 0.f);
  int bi = ((qx - 1) * 32 + (qy - 1)) * 32 + (qz - 1);
  const float* xb = x + c0 * PLANE + bi;
  return make_float4(xb[0], xb[PLANE], xb[2 * PLANE], xb[3 * PLANE]);
}

__global__ __launch_bounds__(256) void deform_fallback(
    const float* __restrict__ x, const float* __restrict__ offset,
    const float* __restrict__ W, float* __restrict__ out) {
  __shared__ float red[8][32][20];

  int tid = threadIdx.x;
  int k = tid & 31;
  int c4 = (tid >> 5) & 3;
  int th = tid >> 7;
  int i = blockIdx.x >> 5;
  int j = blockIdx.x & 31;

  float4 acc0 = make_float4(0.f, 0.f, 0.f, 0.f);
  float4 acc1 = acc0, acc2 = acc0, acc3 = acc0;

  for (int t = th; t < 27; t += 2) {
    int src;
    float bx, by, bz;
    tap_meta(t, i, j, k, src, bx, by, bz);
    float px = bx + offset[src];
    float py = by + offset[src + 27 * PLANE];
    float pz = bz + offset[src + 54 * PLANE];

    int q0x, q1x, q0y, q1y, q0z, q1z;
    float lx, hx, ly, hy, lz, hz;
    axis_interp(px, q0x, q1x, lx, hx);
    axis_interp(py, q0y, q1y, ly, hy);
    axis_interp(pz, q0z, q1z, lz, hz);

    float a00 = ly * lz, a01 = ly * hz, a10 = hy * lz, a11 = hy * hz;
    float w000 = lx * a00, w001 = lx * a01, w010 = lx * a10, w011 = lx * a11;
    float w100 = hx * a00, w101 = hx * a01, w110 = hx * a10, w111 = hx * a11;

    int c0 = c4 * 4;
    float4 s4;
    s4 = f4scale(w000, corner_direct(x, q0x, q0y, q0z, c0));
    s4 = f4fma(w001, corner_direct(x, q0x, q0y, q1z, c0), s4);
    s4 = f4fma(w010, corner_direct(x, q0x, q1y, q0z, c0), s4);
    s4 = f4fma(w011, corner_direct(x, q0x, q1y, q1z, c0), s4);
    s4 = f4fma(w100, corner_direct(x, q1x, q0y, q0z, c0), s4);
    s4 = f4fma(w101, corner_direct(x, q1x, q0y, q1z, c0), s4);
    s4 = f4fma(w110, corner_direct(x, q1x, q1y, q0z, c0), s4);
    s4 = f4fma(w111, corner_direct(x, q1x, q1y, q1z, c0), s4);

    float sarr[4] = {s4.x, s4.y, s4.z, s4.w};
#pragma unroll
    for (int cc = 0; cc < 4; cc++) {
      float s = sarr[cc];
      const float* wr = W + (c4 * 4 + cc) * 27 + t;
      acc0.x = fmaf(s, wr[0 * 432], acc0.x);
      acc0.y = fmaf(s, wr[1 * 432], acc0.y);
      acc0.z = fmaf(s, wr[2 * 432], acc0.z);
      acc0.w = fmaf(s, wr[3 * 432], acc0.w);
      acc1.x = fmaf(s, wr[4 * 432], acc1.x);
      acc1.y = fmaf(s, wr[5 * 432], acc1.y);
      acc1.z = fmaf(s, wr[6 * 432], acc1.z);
      acc1.w = fmaf(s, wr[7 * 432], acc1.w);
      acc2.x = fmaf(s, wr[8 * 432], acc2.x);
      acc2.y = fmaf(s, wr[9 * 432], acc2.y);
      acc2.z = fmaf(s, wr[10 * 432], acc2.z);
      acc2.w = fmaf(s, wr[11 * 432], acc2.w);
      acc3.x = fmaf(s, wr[12 * 432], acc3.x);
      acc3.y = fmaf(s, wr[13 * 432], acc3.y);
      acc3.z = fmaf(s, wr[14 * 432], acc3.z);
      acc3.w = fmaf(s, wr[15 * 432], acc3.w);
    }
  }

  int grp = th * 4 + c4;
  float* r = &red[grp][k][0];
  ((float4*)r)[0] = acc0;
  ((float4*)r)[1] = acc1;
  ((float4*)r)[2] = acc2;
  ((float4*)r)[3] = acc3;
  __syncthreads();

#pragma unroll
  for (int rep = 0; rep < 2; rep++) {
    int idx = tid + rep * 256;
    int o = idx >> 5;
    int kk2 = idx & 31;
    float v = 0.f;
#pragma unroll
    for (int g = 0; g < 8; g++) v += red[g][kk2][o];
    out[((o * 32 + i) * 32 + j) * 32 + kk2] = v;
  }
}

extern "C" void kernel_launch(void* const* d_in, const int* in_sizes, int n_in,
                              void* d_out, int out_size, void* d_ws, size_t ws_size,
                              hipStream_t stream) {
  const float* x = (const float*)d_in[0];      // 16*32^3
  const float* off = (const float*)d_in[1];    // 81*32^3
  const float* W = (const float*)d_in[2];      // 16*16*27
  float* out = (float*)d_out;

  const size_t WT_F = 6912;
  const size_t XP_F = (size_t)PADDIM * PADDIM * PADDIM * NCH;  // 628864
  const size_t NEED = (WT_F + XP_F) * 4;                       // ~2.5 MB

  if (ws_size >= NEED) {
    float* wt = (float*)d_ws;
    float* xp = wt + WT_F;           // byte 27648, 16B-aligned
    prep_small<<<2457 + 27, 256, 0, stream>>>(x, W, xp, wt);
    deform_main9<<<1024, 512, 0, stream>>>(off, wt, xp, out);
  } else {
    deform_fallback<<<1024, 256, 0, stream>>>(x, off, W, out);
  }
}

// Round 10
// 127.683 us; speedup vs baseline: 1.0433x; 1.0433x over previous
//
#include <hip/hip_runtime.h>

// DeformConv3D_alternative: B=1, C=16->16, S=32, ks=3, N=27, fp32.
// R10: R9 + XCD-aware block remap. Model (validated by R7-R9 invariance):
// main kernel is L1-fill-queue x fill-latency bound (0.17 lines/cyc/CU ~=
// 64-deep queue / ~400cyc L3-class latency). Default b%8 round-robin scatters
// same-i blocks across XCDs -> each XCD streams ALL of xp+offsets through its
// 4MB L2 -> thrash -> L3 fills. Remap pins i in [4*xcd, 4*xcd+4) per XCD:
// xp slab ~440 KB + offset slab ~1.3 MB stay L2-resident -> ~200cyc fills,
// 2x fill throughput. FETCH is all offset-staging traffic (26.5 MB = 5/3
// lines/run model); same-XCD adjacent-j sharing should drop it to ~15 MB.
// Fixed ~58-60 us harness overhead (restore+poison) measured across R0-R9.

#define NCH 16
#define PADDIM 34
#define PLANE 32768            // 32*32*32

__device__ __forceinline__ float4 f4fma(float s, const float4 a, const float4 b) {
  return make_float4(fmaf(s, a.x, b.x), fmaf(s, a.y, b.y),
                     fmaf(s, a.z, b.z), fmaf(s, a.w, b.w));
}
__device__ __forceinline__ float4 f4scale(float s, const float4 a) {
  return make_float4(s * a.x, s * a.y, s * a.z, s * a.w);
}

// Reference semantics: q0=clip(floor(p),0,33), q1=clip(floor(p)+1,0,33);
// mask=(p<1)|(p>32) -> p=floor(p); p=clip(p,0,33); l=1+q0-p; h=1-q1+p.
__device__ __forceinline__ void axis_interp(float p, int& q0, int& q1,
                                            float& lo, float& hi) {
  float fl = floorf(p);
  int fi = (int)fl;
  q0 = min(max(fi, 0), 33);
  q1 = min(max(fi + 1, 0), 33);
  float pm = (p < 1.f || p > 32.f) ? fl : p;
  pm = fminf(fmaxf(pm, 0.f), 33.f);
  lo = 1.f + (float)q0 - pm;
  hi = 1.f - (float)q1 + pm;
}

// ---- single prep kernel: xp (padded channel-last x) + Wt transpose
__global__ void prep_small(const float* __restrict__ x,
                           const float* __restrict__ W,
                           float* __restrict__ xp, float* __restrict__ wt) {
  int b = blockIdx.x;
  if (b < 2457) {
    int idx = b * 256 + threadIdx.x;
    if (idx >= PADDIM * PADDIM * PADDIM * NCH) return;
    int c = idx & 15;
    int site = idx >> 4;
    int qz = site % PADDIM;
    int t = site / PADDIM;
    int qy = t % PADDIM;
    int qx = t / PADDIM;
    float v = 0.f;
    if (qx >= 1 && qx <= 32 && qy >= 1 && qy <= 32 && qz >= 1 && qz <= 32)
      v = x[c * PLANE + ((qx - 1) * 32 + (qy - 1)) * 32 + (qz - 1)];
    xp[idx] = v;
  } else {
    int idx = (b - 2457) * 256 + threadIdx.x;   // [0, 6912)
    if (idx >= 6912) return;
    int o = idx & 15;
    int r = idx >> 4;
    int cw = r & 15;
    int t = r >> 4;
    wt[idx] = W[(o * 16 + cw) * 27 + t];        // Wt[t][cin][o]
  }
}

// ---- main: tid = kk(4b) | c4(2b) | kh(1b) | th(2b); grid = 1024.
// Block remap: xcd = b&7 (HW round-robin), i in [4*xcd, 4*xcd+4) -> each
// XCD's L2 holds a 4-row xp slab + its offset slab for the kernel duration.
__global__ __launch_bounds__(512, 8) void deform_main10(
    const float* __restrict__ off, const float* __restrict__ Wt,
    const float* __restrict__ xp, float* __restrict__ out) {
  __shared__ float sOff[2916];       // 3 comp * 3 alpha * 27 n * 12 pos
  __shared__ float red[4][32][20];   // [th][k][o(+pad)]

  int tid = threadIdx.x;
  int b = blockIdx.x;
  int xcd = b & 7;
  int local = b >> 3;                // [0,128)
  int i = xcd * 4 + (local & 3);
  int j = local >> 2;                // [0,32)

  // --- stage offset working set into LDS (nt: stream, don't keep) ---
#pragma unroll
  for (int it = 0; it < 6; it++) {
    int s = tid + it * 512;
    if (s < 2916) {
      int comp = s / 972;
      int rem = s - comp * 972;
      int alpha = rem / 324;
      int rem2 = rem - alpha * 324;
      int n = rem2 / 12;
      int pos = rem2 - n * 12;
      int aj = 2 * alpha + j;
      int r3 = aj % 3;
      int wp = 10 * alpha + aj / 3;
      int dp = min((r3 * 96) / 9 + pos, 31);
      sOff[s] = __builtin_nontemporal_load(
          &off[(comp * 27 + n) * PLANE + i * 1024 + wp * 32 + dp]);
    }
  }
  __syncthreads();

  int kk = tid & 15;                 // k within half
  int c4 = (tid >> 4) & 3;           // channel quad (4 per wave -> full line)
  int kh = (tid >> 6) & 1;           // k half
  int th = tid >> 7;                 // tap phase: t = th, th+4, ...
  int k = kh * 16 + kk;

  float4 acc0 = make_float4(0.f, 0.f, 0.f, 0.f);
  float4 acc1 = acc0, acc2 = acc0, acc3 = acc0;

  const float4* xp4 = (const float4*)xp;
  const float4* Wt4 = (const float4*)Wt;

  for (int t = th; t < 27; t += 4) {
    int alpha = t / 9;
    int t3 = t / 3;
    int beta = t3 % 3;
    int gamma = t - t3 * 3;
    int G = 3072 * alpha + 96 * j + 3 * k + gamma;
    int wp = G / 288;
    int u = G - wp * 288;
    int dp = u / 9;
    int m = u - dp * 9;
    int n = 9 * beta + m;
    int aj = 2 * alpha + j;
    int dp_lo = ((aj % 3) * 96) / 9;
    int lidx = (alpha * 27 + n) * 12 + (dp - dp_lo);

    float ox = sOff[lidx];
    float oy = sOff[lidx + 972];
    float oz = sOff[lidx + 1944];

    int md3 = m / 3;
    float px = (float)(i + beta) + ox;
    float py = (float)(wp + md3) + oy;
    float pz = (float)(dp + m - md3 * 3) + oz;

    int q0x, q1x, q0y, q1y, q0z, q1z;
    float lx, hx, ly, hy, lz, hz;
    axis_interp(px, q0x, q1x, lx, hx);
    axis_interp(py, q0y, q1y, ly, hy);
    axis_interp(pz, q0z, q1z, lz, hz);

    float a00 = ly * lz, a01 = ly * hz, a10 = hy * lz, a11 = hy * hz;
    float w000 = lx * a00, w001 = lx * a01, w010 = lx * a10, w011 = lx * a11;
    float w100 = hx * a00, w101 = hx * a01, w110 = hx * a10, w111 = hx * a11;

    int b00 = (q0x * PADDIM + q0y) * PADDIM;
    int b01 = (q0x * PADDIM + q1y) * PADDIM;
    int b10 = (q1x * PADDIM + q0y) * PADDIM;
    int b11 = (q1x * PADDIM + q1y) * PADDIM;
    float4 s4;
    s4 = f4scale(w000, xp4[(b00 + q0z) * 4 + c4]);
    s4 = f4fma(w001, xp4[(b00 + q1z) * 4 + c4], s4);
    s4 = f4fma(w010, xp4[(b01 + q0z) * 4 + c4], s4);
    s4 = f4fma(w011, xp4[(b01 + q1z) * 4 + c4], s4);
    s4 = f4fma(w100, xp4[(b10 + q0z) * 4 + c4], s4);
    s4 = f4fma(w101, xp4[(b10 + q1z) * 4 + c4], s4);
    s4 = f4fma(w110, xp4[(b11 + q0z) * 4 + c4], s4);
    s4 = f4fma(w111, xp4[(b11 + q1z) * 4 + c4], s4);

    float sarr[4] = {s4.x, s4.y, s4.z, s4.w};
    int wb = t * 64 + c4 * 16;
#pragma unroll
    for (int cc = 0; cc < 4; cc++) {
      float s = sarr[cc];
      acc0 = f4fma(s, Wt4[wb + cc * 4 + 0], acc0);
      acc1 = f4fma(s, Wt4[wb + cc * 4 + 1], acc1);
      acc2 = f4fma(s, Wt4[wb + cc * 4 + 2], acc2);
      acc3 = f4fma(s, Wt4[wb + cc * 4 + 3], acc3);
    }
  }

  // --- reduce across c4 (lane bits 4,5) in-wave ---
#pragma unroll
  for (int mask = 16; mask <= 32; mask <<= 1) {
    acc0.x += __shfl_xor(acc0.x, mask); acc0.y += __shfl_xor(acc0.y, mask);
    acc0.z += __shfl_xor(acc0.z, mask); acc0.w += __shfl_xor(acc0.w, mask);
    acc1.x += __shfl_xor(acc1.x, mask); acc1.y += __shfl_xor(acc1.y, mask);
    acc1.z += __shfl_xor(acc1.z, mask); acc1.w += __shfl_xor(acc1.w, mask);
    acc2.x += __shfl_xor(acc2.x, mask); acc2.y += __shfl_xor(acc2.y, mask);
    acc2.z += __shfl_xor(acc2.z, mask); acc2.w += __shfl_xor(acc2.w, mask);
    acc3.x += __shfl_xor(acc3.x, mask); acc3.y += __shfl_xor(acc3.y, mask);
    acc3.z += __shfl_xor(acc3.z, mask); acc3.w += __shfl_xor(acc3.w, mask);
  }

  if (c4 == 0) {
    float* r = &red[th][k][0];
    ((float4*)r)[0] = acc0;
    ((float4*)r)[1] = acc1;
    ((float4*)r)[2] = acc2;
    ((float4*)r)[3] = acc3;
  }
  __syncthreads();

  // --- 4-way tap-phase reduction + nontemporal store ---
  int o = tid >> 5;                  // 0..15
  int kr = tid & 31;
  float v = red[0][kr][o] + red[1][kr][o] + red[2][kr][o] + red[3][kr][o];
  __builtin_nontemporal_store(v, &out[((o * 32 + i) * 32 + j) * 32 + kr]);
}

// ---- fallback (no workspace): direct bounds-checked reads, 1 kernel
__device__ __forceinline__ void tap_meta(int t, int i, int j, int k,
                                         int& src, float& bx, float& by,
                                         float& bz) {
  int alpha = t / 9;
  int beta = (t / 3) % 3;
  int gamma = t - (t / 3) * 3;
  int G = 3072 * alpha + 96 * j + 3 * k + gamma;
  int wp = G / 288;
  int u = G - wp * 288;
  int dp = u / 9;
  int m = u - dp * 9;
  int n = 9 * beta + m;
  src = n * PLANE + i * 1024 + wp * 32 + dp;
  int md3 = m / 3;
  bx = (float)(i + beta);
  by = (float)(wp + md3);
  bz = (float)(dp + m - md3 * 3);
}

__device__ __forceinline__ float4 corner_direct(const float* __restrict__ x,
                                                int qx, int qy, int qz, int c0) {
  if (qx < 1 || qx > 32 || qy < 1 || qy > 32 || qz < 1 || qz > 32)
    return make_float4(0.f, 0.f, 0.f, 0.f);
  int bi = ((qx - 1) * 32 + (qy - 1)) * 32 + (qz - 1);
  const float* xb = x + c0 * PLANE + bi;
  return make_float4(xb[0], xb[PLANE], xb[2 * PLANE], xb[3 * PLANE]);
}

__global__ __launch_bounds__(256) void deform_fallback(
    const float* __restrict__ x, const float* __restrict__ offset,
    const float* __restrict__ W, float* __restrict__ out) {
  __shared__ float red[8][32][20];

  int tid = threadIdx.x;
  int k = tid & 31;
  int c4 = (tid >> 5) & 3;
  int th = tid >> 7;
  int i = blockIdx.x >> 5;
  int j = blockIdx.x & 31;

  float4 acc0 = make_float4(0.f, 0.f, 0.f, 0.f);
  float4 acc1 = acc0, acc2 = acc0, acc3 = acc0;

  for (int t = th; t < 27; t += 2) {
    int src;
    float bx, by, bz;
    tap_meta(t, i, j, k, src, bx, by, bz);
    float px = bx + offset[src];
    float py = by + offset[src + 27 * PLANE];
    float pz = bz + offset[src + 54 * PLANE];

    int q0x, q1x, q0y, q1y, q0z, q1z;
    float lx, hx, ly, hy, lz, hz;
    axis_interp(px, q0x, q1x, lx, hx);
    axis_interp(py, q0y, q1y, ly, hy);
    axis_interp(pz, q0z, q1z, lz, hz);

    float a00 = ly * lz, a01 = ly * hz, a10 = hy * lz, a11 = hy * hz;
    float w000 = lx * a00, w001 = lx * a01, w010 = lx * a10, w011 = lx * a11;
    float w100 = hx * a00, w101 = hx * a01, w110 = hx * a10, w111 = hx * a11;

    int c0 = c4 * 4;
    float4 s4;
    s4 = f4scale(w000, corner_direct(x, q0x, q0y, q0z, c0));
    s4 = f4fma(w001, corner_direct(x, q0x, q0y, q1z, c0), s4);
    s4 = f4fma(w010, corner_direct(x, q0x, q1y, q0z, c0), s4);
    s4 = f4fma(w011, corner_direct(x, q0x, q1y, q1z, c0), s4);
    s4 = f4fma(w100, corner_direct(x, q1x, q0y, q0z, c0), s4);
    s4 = f4fma(w101, corner_direct(x, q1x, q0y, q1z, c0), s4);
    s4 = f4fma(w110, corner_direct(x, q1x, q1y, q0z, c0), s4);
    s4 = f4fma(w111, corner_direct(x, q1x, q1y, q1z, c0), s4);

    float sarr[4] = {s4.x, s4.y, s4.z, s4.w};
#pragma unroll
    for (int cc = 0; cc < 4; cc++) {
      float s = sarr[cc];
      const float* wr = W + (c4 * 4 + cc) * 27 + t;
      acc0.x = fmaf(s, wr[0 * 432], acc0.x);
      acc0.y = fmaf(s, wr[1 * 432], acc0.y);
      acc0.z = fmaf(s, wr[2 * 432], acc0.z);
      acc0.w = fmaf(s, wr[3 * 432], acc0.w);
      acc1.x = fmaf(s, wr[4 * 432], acc1.x);
      acc1.y = fmaf(s, wr[5 * 432], acc1.y);
      acc1.z = fmaf(s, wr[6 * 432], acc1.z);
      acc1.w = fmaf(s, wr[7 * 432], acc1.w);
      acc2.x = fmaf(s, wr[8 * 432], acc2.x);
      acc2.y = fmaf(s, wr[9 * 432], acc2.y);
      acc2.z = fmaf(s, wr[10 * 432], acc2.z);
      acc2.w = fmaf(s, wr[11 * 432], acc2.w);
      acc3.x = fmaf(s, wr[12 * 432], acc3.x);
      acc3.y = fmaf(s, wr[13 * 432], acc3.y);
      acc3.z = fmaf(s, wr[14 * 432], acc3.z);
      acc3.w = fmaf(s, wr[15 * 432], acc3.w);
    }
  }

  int grp = th * 4 + c4;
  float* r = &red[grp][k][0];
  ((float4*)r)[0] = acc0;
  ((float4*)r)[1] = acc1;
  ((float4*)r)[2] = acc2;
  ((float4*)r)[3] = acc3;
  __syncthreads();

#pragma unroll
  for (int rep = 0; rep < 2; rep++) {
    int idx = tid + rep * 256;
    int o = idx >> 5;
    int kk2 = idx & 31;
    float v = 0.f;
#pragma unroll
    for (int g = 0; g < 8; g++) v += red[g][kk2][o];
    out[((o * 32 + i) * 32 + j) * 32 + kk2] = v;
  }
}

extern "C" void kernel_launch(void* const* d_in, const int* in_sizes, int n_in,
                              void* d_out, int out_size, void* d_ws, size_t ws_size,
                              hipStream_t stream) {
  const float* x = (const float*)d_in[0];      // 16*32^3
  const float* off = (const float*)d_in[1];    // 81*32^3
  const float* W = (const float*)d_in[2];      // 16*16*27
  float* out = (float*)d_out;

  const size_t WT_F = 6912;
  const size_t XP_F = (size_t)PADDIM * PADDIM * PADDIM * NCH;  // 628864
  const size_t NEED = (WT_F + XP_F) * 4;                       // ~2.5 MB

  if (ws_size >= NEED) {
    float* wt = (float*)d_ws;
    float* xp = wt + WT_F;           // byte 27648, 16B-aligned
    prep_small<<<2457 + 27, 256, 0, stream>>>(x, W, xp, wt);
    deform_main10<<<1024, 512, 0, stream>>>(off, wt, xp, out);
  } else {
    deform_fallback<<<1024, 256, 0, stream>>>(x, off, W, out);
  }
}